// Round 1
// baseline (7476.888 us; speedup 1.0000x reference)
//
#include <hip/hip_runtime.h>

// STGraphConstructor: C[b] = tanh(relu(E[b] @ E[b]^T)),
// E[b] = concat(spatial[b] (N=2048,D=64), temporal[b] (T=168,D=64)), M = 2216.
// fp32 in / fp32 out. Output 314 MB -> ~50us write floor; fp32 FMA ~64us.

constexpr int Bsz = 16;
constexpr int Nsp = 2048;
constexpr int Ttm = 168;
constexpr int D   = 64;
constexpr int M   = Nsp + Ttm;   // 2216
constexpr int TILE = 64;
constexpr int LDSS = 68;         // LDS row stride (floats): 16B-aligned, bank-step 4

__global__ __launch_bounds__(256, 4) void stgraph_kernel(
    const float* __restrict__ spatial,
    const float* __restrict__ temporal,
    float* __restrict__ out)
{
    __shared__ float As[TILE * LDSS];
    __shared__ float Bs[TILE * LDSS];

    const int tid    = threadIdx.x;
    const int tile_j = blockIdx.x;
    const int tile_i = blockIdx.y;
    const int b      = blockIdx.z;

    const float* sp_b = spatial  + (size_t)b * Nsp * D;
    const float* tp_b = temporal + (size_t)b * Ttm * D;

    // ---- stage tiles: 1024 float4 per tile, 256 threads x 4 iters ----
    #pragma unroll
    for (int it = 0; it < 4; ++it) {
        const int f4  = tid + 256 * it;   // 0..1023
        const int row = f4 >> 4;          // 0..63
        const int c4  = f4 & 15;          // float4 index within row
        // A tile (rows of E at tile_i)
        {
            const int gi = tile_i * TILE + row;
            float4 v = make_float4(0.f, 0.f, 0.f, 0.f);
            if (gi < M) {
                const float* src = (gi < Nsp) ? (sp_b + (size_t)gi * D)
                                              : (tp_b + (size_t)(gi - Nsp) * D);
                v = *(const float4*)(src + c4 * 4);
            }
            *(float4*)(&As[row * LDSS + c4 * 4]) = v;
        }
        // B tile (rows of E at tile_j)
        {
            const int gj = tile_j * TILE + row;
            float4 v = make_float4(0.f, 0.f, 0.f, 0.f);
            if (gj < M) {
                const float* src = (gj < Nsp) ? (sp_b + (size_t)gj * D)
                                              : (tp_b + (size_t)(gj - Nsp) * D);
                v = *(const float4*)(src + c4 * 4);
            }
            *(float4*)(&Bs[row * LDSS + c4 * 4]) = v;
        }
    }
    __syncthreads();

    // ---- 4x4 micro-tile per thread; interleaved mapping (stride 16) ----
    const int tx = tid & 15;   // col lane
    const int ty = tid >> 4;   // row lane
    float acc[4][4] = {};

    #pragma unroll
    for (int k4 = 0; k4 < 16; ++k4) {
        float4 a4[4], b4[4];
        #pragma unroll
        for (int r = 0; r < 4; ++r)
            a4[r] = *(const float4*)(&As[(ty + 16 * r) * LDSS + k4 * 4]);
        #pragma unroll
        for (int c = 0; c < 4; ++c)
            b4[c] = *(const float4*)(&Bs[(tx + 16 * c) * LDSS + k4 * 4]);
        #pragma unroll
        for (int r = 0; r < 4; ++r) {
            #pragma unroll
            for (int c = 0; c < 4; ++c) {
                acc[r][c] += a4[r].x * b4[c].x + a4[r].y * b4[c].y
                           + a4[r].z * b4[c].z + a4[r].w * b4[c].w;
            }
        }
    }

    // ---- epilogue: tanh(relu(x)) = 1 - 2/(exp(2x)+1), store fp32 ----
    float* out_b = out + (size_t)b * M * M;
    #pragma unroll
    for (int r = 0; r < 4; ++r) {
        const int gi = tile_i * TILE + ty + 16 * r;
        if (gi >= M) continue;
        #pragma unroll
        for (int c = 0; c < 4; ++c) {
            const int gj = tile_j * TILE + tx + 16 * c;
            if (gj >= M) continue;
            const float x = fmaxf(acc[r][c], 0.0f);
            const float e = __expf(2.0f * x);      // inf for large x -> t = 1
            const float t = 1.0f - 2.0f / (e + 1.0f);
            out_b[(size_t)gi * M + gj] = t;
        }
    }
}

extern "C" void kernel_launch(void* const* d_in, const int* in_sizes, int n_in,
                              void* d_out, int out_size, void* d_ws, size_t ws_size,
                              hipStream_t stream) {
    const float* spatial  = (const float*)d_in[0];
    const float* temporal = (const float*)d_in[1];
    float* out = (float*)d_out;

    dim3 block(256);
    dim3 grid((M + TILE - 1) / TILE, (M + TILE - 1) / TILE, Bsz);  // 35 x 35 x 16
    stgraph_kernel<<<grid, block, 0, stream>>>(spatial, temporal, out);
}

// Round 2
// 483.003 us; speedup vs baseline: 15.4800x; 15.4800x over previous
//
#include <hip/hip_runtime.h>

// STGraphConstructor: C[b] = tanh(relu(E[b] @ E[b]^T)),
// E[b] = concat(spatial[b] (N=2048,D=64), temporal[b] (T=168,D=64)), M = 2216.
// R2: 128x128 tiles (halve staging traffic) + nontemporal output stores
// (keep 9 MB of inputs L2-resident against the 314 MB write stream).

constexpr int Bsz = 16;
constexpr int Nsp = 2048;
constexpr int Ttm = 168;
constexpr int D   = 64;
constexpr int M   = Nsp + Ttm;   // 2216
constexpr int TILE = 128;
constexpr int LDSS = 68;         // floats; 272 B row stride: 16B-aligned, conflict-free patterns

__global__ __launch_bounds__(256, 2) void stgraph_kernel(
    const float* __restrict__ spatial,
    const float* __restrict__ temporal,
    float* __restrict__ out)
{
    __shared__ float As[TILE * LDSS];
    __shared__ float Bs[TILE * LDSS];

    const int tid    = threadIdx.x;
    const int tile_j = blockIdx.x;
    const int tile_i = blockIdx.y;
    const int b      = blockIdx.z;

    const float* sp_b = spatial  + (size_t)b * Nsp * D;
    const float* tp_b = temporal + (size_t)b * Ttm * D;

    // ---- stage A tile: 128 rows x 16 float4 = 2048 float4, 256 thr x 8 ----
    #pragma unroll
    for (int it = 0; it < 8; ++it) {
        const int f4  = tid + 256 * it;   // 0..2047
        const int row = f4 >> 4;          // 0..127
        const int c4  = f4 & 15;
        const int gi  = tile_i * TILE + row;
        float4 v = make_float4(0.f, 0.f, 0.f, 0.f);
        if (gi < M) {
            const float* src = (gi < Nsp) ? (sp_b + (size_t)gi * D)
                                          : (tp_b + (size_t)(gi - Nsp) * D);
            v = *(const float4*)(src + c4 * 4);
        }
        *(float4*)(&As[row * LDSS + c4 * 4]) = v;
    }
    // ---- stage B tile ----
    #pragma unroll
    for (int it = 0; it < 8; ++it) {
        const int f4  = tid + 256 * it;
        const int row = f4 >> 4;
        const int c4  = f4 & 15;
        const int gj  = tile_j * TILE + row;
        float4 v = make_float4(0.f, 0.f, 0.f, 0.f);
        if (gj < M) {
            const float* src = (gj < Nsp) ? (sp_b + (size_t)gj * D)
                                          : (tp_b + (size_t)(gj - Nsp) * D);
            v = *(const float4*)(src + c4 * 4);
        }
        *(float4*)(&Bs[row * LDSS + c4 * 4]) = v;
    }
    __syncthreads();

    // ---- 8x8 micro-tile per thread; interleaved mapping (stride 16) ----
    // a-reads: 16-lane broadcast, conflict-free. b-reads: 16 rows, 2-way = free.
    const int tx = tid & 15;
    const int ty = tid >> 4;
    float acc[8][8] = {};

    #pragma unroll 2
    for (int k4 = 0; k4 < 16; ++k4) {
        float4 a4[8], b4[8];
        #pragma unroll
        for (int r = 0; r < 8; ++r)
            a4[r] = *(const float4*)(&As[(ty + 16 * r) * LDSS + k4 * 4]);
        #pragma unroll
        for (int c = 0; c < 8; ++c)
            b4[c] = *(const float4*)(&Bs[(tx + 16 * c) * LDSS + k4 * 4]);
        #pragma unroll
        for (int r = 0; r < 8; ++r) {
            #pragma unroll
            for (int c = 0; c < 8; ++c) {
                acc[r][c] += a4[r].x * b4[c].x + a4[r].y * b4[c].y
                           + a4[r].z * b4[c].z + a4[r].w * b4[c].w;
            }
        }
    }

    // ---- epilogue: tanh(relu(x)) = 1 - 2/(exp(2x)+1); nontemporal stores ----
    float* out_b = out + (size_t)b * M * M;
    #pragma unroll
    for (int r = 0; r < 8; ++r) {
        const int gi = tile_i * TILE + ty + 16 * r;
        if (gi >= M) continue;
        float* orow = out_b + (size_t)gi * M;
        #pragma unroll
        for (int c = 0; c < 8; ++c) {
            const int gj = tile_j * TILE + tx + 16 * c;
            if (gj >= M) continue;
            const float x = fmaxf(acc[r][c], 0.0f);
            const float e = __expf(2.0f * x);      // inf for large x -> t = 1
            const float t = 1.0f - 2.0f / (e + 1.0f);
            __builtin_nontemporal_store(t, orow + gj);
        }
    }
}

extern "C" void kernel_launch(void* const* d_in, const int* in_sizes, int n_in,
                              void* d_out, int out_size, void* d_ws, size_t ws_size,
                              hipStream_t stream) {
    const float* spatial  = (const float*)d_in[0];
    const float* temporal = (const float*)d_in[1];
    float* out = (float*)d_out;

    dim3 block(256);
    dim3 grid((M + TILE - 1) / TILE, (M + TILE - 1) / TILE, Bsz);  // 18 x 18 x 16
    stgraph_kernel<<<grid, block, 0, stream>>>(spatial, temporal, out);
}

// Round 3
// 467.009 us; speedup vs baseline: 16.0101x; 1.0342x over previous
//
#include <hip/hip_runtime.h>
#include <stdint.h>

// STGraphConstructor: C[b] = tanh(relu(E[b] @ E[b]^T)), E = concat(spatial, temporal)
// B=16, N=2048, T=168, D=64, M=2216. fp32 in/out.
// R3: split-bf16 MFMA (hi/lo decomposition, 3 MFMAs, err ~1e-4 << 2e-2) to break
// the fp32-vector compute wall; plain (mergeable) 128B stores to kill the 1.5x
// write inflation seen with misaligned nontemporal 64B segments.

constexpr int Bsz = 16;
constexpr int Nsp = 2048;
constexpr int Ttm = 168;
constexpr int D   = 64;
constexpr int M   = Nsp + Ttm;   // 2216
constexpr int TILE = 128;
constexpr int LROW = 72;         // ushort stride per LDS row (144 B, 16B-aligned)

typedef __attribute__((ext_vector_type(8)))  short bf16x8;   // 8 bf16 = 4 VGPRs
typedef __attribute__((ext_vector_type(16))) float f32x16;   // 32x32 acc

__device__ inline void split_bf16(float x, unsigned short& h, unsigned short& l) {
    union { float f; uint32_t u; } a; a.f = x;
    uint32_t hu = (a.u + 0x7FFFu + ((a.u >> 16) & 1u)) >> 16;   // RNE to bf16
    h = (unsigned short)hu;
    union { uint32_t u; float f; } hf; hf.u = hu << 16;
    union { float f; uint32_t u; } r; r.f = x - hf.f;           // exact residual
    uint32_t lu = (r.u + 0x7FFFu + ((r.u >> 16) & 1u)) >> 16;
    l = (unsigned short)lu;
}

__global__ __launch_bounds__(256, 2) void stgraph_kernel(
    const float* __restrict__ spatial,
    const float* __restrict__ temporal,
    float* __restrict__ out)
{
    __shared__ __align__(16) unsigned short Ah[TILE * LROW];
    __shared__ __align__(16) unsigned short Al[TILE * LROW];
    __shared__ __align__(16) unsigned short Bh[TILE * LROW];
    __shared__ __align__(16) unsigned short Bl[TILE * LROW];

    const int tid    = threadIdx.x;
    const int tile_j = blockIdx.x;
    const int tile_i = blockIdx.y;
    const int b      = blockIdx.z;

    const float* sp_b = spatial  + (size_t)b * Nsp * D;
    const float* tp_b = temporal + (size_t)b * Ttm * D;

    // ---- stage + convert: 128 rows x 16 float4 per tile, 256 thr x 8 iters ----
    #pragma unroll
    for (int it = 0; it < 8; ++it) {
        const int f4  = tid + 256 * it;   // 0..2047
        const int row = f4 >> 4;          // 0..127
        const int c4  = f4 & 15;          // float4 index in row
        // A tile
        {
            const int gi = tile_i * TILE + row;
            float4 v = make_float4(0.f, 0.f, 0.f, 0.f);
            if (gi < M) {
                const float* src = (gi < Nsp) ? (sp_b + (size_t)gi * D)
                                              : (tp_b + (size_t)(gi - Nsp) * D);
                v = *(const float4*)(src + c4 * 4);
            }
            unsigned short h[4], l[4];
            split_bf16(v.x, h[0], l[0]); split_bf16(v.y, h[1], l[1]);
            split_bf16(v.z, h[2], l[2]); split_bf16(v.w, h[3], l[3]);
            *(uint2*)(&Ah[row * LROW + c4 * 4]) = *(const uint2*)h;
            *(uint2*)(&Al[row * LROW + c4 * 4]) = *(const uint2*)l;
        }
        // B tile
        {
            const int gj = tile_j * TILE + row;
            float4 v = make_float4(0.f, 0.f, 0.f, 0.f);
            if (gj < M) {
                const float* src = (gj < Nsp) ? (sp_b + (size_t)gj * D)
                                              : (tp_b + (size_t)(gj - Nsp) * D);
                v = *(const float4*)(src + c4 * 4);
            }
            unsigned short h[4], l[4];
            split_bf16(v.x, h[0], l[0]); split_bf16(v.y, h[1], l[1]);
            split_bf16(v.z, h[2], l[2]); split_bf16(v.w, h[3], l[3]);
            *(uint2*)(&Bh[row * LROW + c4 * 4]) = *(const uint2*)h;
            *(uint2*)(&Bl[row * LROW + c4 * 4]) = *(const uint2*)l;
        }
    }
    __syncthreads();

    // ---- MFMA: wave w owns rows 32w..32w+31; 4 col tiles of 32 ----
    const int lane = tid & 63;
    const int w    = tid >> 6;
    const int l31  = lane & 31;
    const int lhi  = lane >> 5;           // k-half select
    const int arow = 32 * w + l31;

    f32x16 acc[4] = {};

    #pragma unroll
    for (int ks = 0; ks < 4; ++ks) {
        const int ko = ks * 16 + 8 * lhi;  // 8 contiguous k per lane
        bf16x8 ahi = *(const bf16x8*)(&Ah[arow * LROW + ko]);
        bf16x8 alo = *(const bf16x8*)(&Al[arow * LROW + ko]);
        #pragma unroll
        for (int t = 0; t < 4; ++t) {
            const int brow = 32 * t + l31;
            bf16x8 bhi = *(const bf16x8*)(&Bh[brow * LROW + ko]);
            bf16x8 blo = *(const bf16x8*)(&Bl[brow * LROW + ko]);
            acc[t] = __builtin_amdgcn_mfma_f32_32x32x16_bf16(ahi, bhi, acc[t], 0, 0, 0);
            acc[t] = __builtin_amdgcn_mfma_f32_32x32x16_bf16(ahi, blo, acc[t], 0, 0, 0);
            acc[t] = __builtin_amdgcn_mfma_f32_32x32x16_bf16(alo, bhi, acc[t], 0, 0, 0);
        }
    }

    // ---- epilogue: tanh(relu(x)) = 1 - 2/(exp(2x)+1); plain stores ----
    // C layout (verified m74/m101): col = lane&31, row = (reg&3)+8*(reg>>2)+4*(lane>>5)
    float* out_b = out + (size_t)b * M * M;
    #pragma unroll
    for (int t = 0; t < 4; ++t) {
        const int gj = tile_j * TILE + 32 * t + l31;
        if (gj >= M) continue;
        #pragma unroll
        for (int r = 0; r < 16; ++r) {
            const int lrow = (r & 3) + 8 * (r >> 2) + 4 * lhi;
            const int gi = tile_i * TILE + 32 * w + lrow;
            if (gi >= M) continue;
            const float x = fmaxf(acc[t][r], 0.0f);
            const float e = __expf(2.0f * x);     // inf for large x -> 1
            const float v = 1.0f - 2.0f / (e + 1.0f);
            out_b[(size_t)gi * M + gj] = v;
        }
    }
}

extern "C" void kernel_launch(void* const* d_in, const int* in_sizes, int n_in,
                              void* d_out, int out_size, void* d_ws, size_t ws_size,
                              hipStream_t stream) {
    const float* spatial  = (const float*)d_in[0];
    const float* temporal = (const float*)d_in[1];
    float* out = (float*)d_out;

    dim3 block(256);
    dim3 grid((M + TILE - 1) / TILE, (M + TILE - 1) / TILE, Bsz);  // 18 x 18 x 16
    stgraph_kernel<<<grid, block, 0, stream>>>(spatial, temporal, out);
}

// Round 5
// 427.305 us; speedup vs baseline: 17.4978x; 1.0929x over previous
//
#include <hip/hip_runtime.h>
#include <stdint.h>

// STGraphConstructor: C[b] = tanh(relu(E[b] @ E[b]^T)), E = concat(spatial, temporal)
// B=16, N=2048, T=168, D=64, M=2216. fp32 in/out.
// R5 = R4 bugfix: epilogue rows were missing the +32*w wave offset (waves clobbered
// rows 0..31; T rows 32..127 left uninitialized -> mirror copied garbage LDS).
// Structure unchanged: upper-triangle tiles only (171 pairs vs 324), mirror via
// LDS transpose, diagonal blocks skip B staging, split-bf16 MFMA.

constexpr int Bsz = 16;
constexpr int Nsp = 2048;
constexpr int Ttm = 168;
constexpr int D   = 64;
constexpr int M   = Nsp + Ttm;            // 2216
constexpr int TILE = 128;
constexpr int NT   = (M + TILE - 1) / TILE;   // 18 tiles
constexpr int NPAIR = NT * (NT + 1) / 2;      // 171 pairs
constexpr int LROW = 72;                  // ushorts per staging row (144 B, 16B-aligned)
constexpr int TROW = 132;                 // floats per transpose row (528 B, 16B-aligned)

typedef __attribute__((ext_vector_type(8)))  short bf16x8;   // 8 bf16 = 4 VGPRs
typedef __attribute__((ext_vector_type(16))) float f32x16;   // 32x32 acc

__device__ inline void split_bf16(float x, unsigned short& h, unsigned short& l) {
    union { float f; uint32_t u; } a; a.f = x;
    uint32_t hu = (a.u + 0x7FFFu + ((a.u >> 16) & 1u)) >> 16;   // RNE to bf16
    h = (unsigned short)hu;
    union { uint32_t u; float f; } hf; hf.u = hu << 16;
    union { float f; uint32_t u; } r; r.f = x - hf.f;           // exact residual
    uint32_t lu = (r.u + 0x7FFFu + ((r.u >> 16) & 1u)) >> 16;
    l = (unsigned short)lu;
}

__device__ inline float act_tanh_relu(float x) {
    const float xr = fmaxf(x, 0.0f);
    const float e  = __expf(2.0f * xr);   // inf for large x -> 1
    return 1.0f - 2.0f / (e + 1.0f);
}

__global__ __launch_bounds__(256, 2) void stgraph_kernel(
    const float* __restrict__ spatial,
    const float* __restrict__ temporal,
    float* __restrict__ out)
{
    // 73728 B pool: 4 bf16 staging planes (18432 B each); transpose view
    // (128*132*4 = 67584 B) overlays it after the compute phase.
    __shared__ __align__(16) unsigned short pool[4 * TILE * LROW];
    unsigned short* Ah = pool;
    unsigned short* Al = pool + 1 * TILE * LROW;
    unsigned short* Bh = pool + 2 * TILE * LROW;
    unsigned short* Bl = pool + 3 * TILE * LROW;
    float* T = (float*)pool;

    const int tid = threadIdx.x;
    const int b   = blockIdx.y;

    // ---- decode upper-triangle pair p -> (ti <= tj) ----
    const int p = blockIdx.x;
    int ti = (int)((37.0f - sqrtf(1369.0f - 8.0f * (float)p)) * 0.5f);
    while (ti * (37 - ti) / 2 > p) --ti;
    while ((ti + 1) * (36 - ti) / 2 <= p) ++ti;
    const int tj = ti + (p - ti * (37 - ti) / 2);
    const bool diag = (ti == tj);

    const float* sp_b = spatial  + (size_t)b * Nsp * D;
    const float* tp_b = temporal + (size_t)b * Ttm * D;

    // ---- stage + split-convert A (and B if off-diagonal) ----
    #pragma unroll
    for (int it = 0; it < 8; ++it) {
        const int f4  = tid + 256 * it;   // 0..2047
        const int row = f4 >> 4;
        const int c4  = f4 & 15;
        const int gi  = ti * TILE + row;
        float4 v = make_float4(0.f, 0.f, 0.f, 0.f);
        if (gi < M) {
            const float* src = (gi < Nsp) ? (sp_b + (size_t)gi * D)
                                          : (tp_b + (size_t)(gi - Nsp) * D);
            v = *(const float4*)(src + c4 * 4);
        }
        unsigned short h[4], l[4];
        split_bf16(v.x, h[0], l[0]); split_bf16(v.y, h[1], l[1]);
        split_bf16(v.z, h[2], l[2]); split_bf16(v.w, h[3], l[3]);
        *(uint2*)(&Ah[row * LROW + c4 * 4]) = *(const uint2*)h;
        *(uint2*)(&Al[row * LROW + c4 * 4]) = *(const uint2*)l;
    }
    if (!diag) {
        #pragma unroll
        for (int it = 0; it < 8; ++it) {
            const int f4  = tid + 256 * it;
            const int row = f4 >> 4;
            const int c4  = f4 & 15;
            const int gj  = tj * TILE + row;
            float4 v = make_float4(0.f, 0.f, 0.f, 0.f);
            if (gj < M) {
                const float* src = (gj < Nsp) ? (sp_b + (size_t)gj * D)
                                              : (tp_b + (size_t)(gj - Nsp) * D);
                v = *(const float4*)(src + c4 * 4);
            }
            unsigned short h[4], l[4];
            split_bf16(v.x, h[0], l[0]); split_bf16(v.y, h[1], l[1]);
            split_bf16(v.z, h[2], l[2]); split_bf16(v.w, h[3], l[3]);
            *(uint2*)(&Bh[row * LROW + c4 * 4]) = *(const uint2*)h;
            *(uint2*)(&Bl[row * LROW + c4 * 4]) = *(const uint2*)l;
        }
    }
    __syncthreads();

    const unsigned short* FBh = diag ? Ah : Bh;
    const unsigned short* FBl = diag ? Al : Bl;

    // ---- MFMA: wave w owns rows 32w..32w+31; 4 col tiles of 32 ----
    const int lane = tid & 63;
    const int w    = tid >> 6;
    const int l31  = lane & 31;
    const int lhi  = lane >> 5;
    const int arow = 32 * w + l31;

    f32x16 acc[4] = {};

    #pragma unroll
    for (int ks = 0; ks < 4; ++ks) {
        const int ko = ks * 16 + 8 * lhi;  // 8 contiguous k per lane
        bf16x8 ahi = *(const bf16x8*)(&Ah[arow * LROW + ko]);
        bf16x8 alo = *(const bf16x8*)(&Al[arow * LROW + ko]);
        #pragma unroll
        for (int t = 0; t < 4; ++t) {
            const int brow = 32 * t + l31;
            bf16x8 bhi = *(const bf16x8*)(&FBh[brow * LROW + ko]);
            bf16x8 blo = *(const bf16x8*)(&FBl[brow * LROW + ko]);
            acc[t] = __builtin_amdgcn_mfma_f32_32x32x16_bf16(ahi, bhi, acc[t], 0, 0, 0);
            acc[t] = __builtin_amdgcn_mfma_f32_32x32x16_bf16(ahi, blo, acc[t], 0, 0, 0);
            acc[t] = __builtin_amdgcn_mfma_f32_32x32x16_bf16(alo, bhi, acc[t], 0, 0, 0);
        }
    }

    // ---- epilogue ----
    // C layout (m74/m101): col = lane&31, row = 32*w + (reg&3) + 8*(reg>>2) + 4*(lane>>5)
    float* out_b = out + (size_t)b * M * M;

    if (!diag) __syncthreads();   // all frag reads done before T overlays staging

    #pragma unroll
    for (int t = 0; t < 4; ++t) {
        const int jl = 32 * t + l31;          // local col
        const int gj = tj * TILE + jl;
        float v[16];
        #pragma unroll
        for (int r = 0; r < 16; ++r) v[r] = act_tanh_relu(acc[t][r]);

        // direct store: row gi, col gj (lane-contiguous cols)
        if (gj < M) {
            #pragma unroll
            for (int r = 0; r < 16; ++r) {
                const int gi = ti * TILE + 32 * w + (r & 3) + 8 * (r >> 2) + 4 * lhi;
                if (gi < M) out_b[(size_t)gi * M + gj] = v[r];
            }
        }
        // transpose write for mirror tile: T[jl][32*w + rowbase .. +3]
        if (!diag) {
            #pragma unroll
            for (int g = 0; g < 4; ++g) {
                const int rowbase = 32 * w + 8 * g + 4 * lhi;
                float4 w4 = make_float4(v[4 * g + 0], v[4 * g + 1],
                                        v[4 * g + 2], v[4 * g + 3]);
                *(float4*)(&T[jl * TROW + rowbase]) = w4;
            }
        }
    }

    if (!diag) {
        __syncthreads();
        // mirror tile: out row = tj*TILE + jl, col = ti*TILE + 4*c4 (+0..3)
        // ti < tj <= 17 -> ti <= 16 -> cols always < M; guard rows only.
        #pragma unroll
        for (int it = 0; it < 16; ++it) {
            const int slot = tid + 256 * it;       // 0..4095
            const int jl   = slot >> 5;            // 0..127
            const int c4   = slot & 31;            // float4 col index
            const int grow = tj * TILE + jl;
            if (grow < M) {
                float4 v4 = *(const float4*)(&T[jl * TROW + 4 * c4]);
                *(float4*)(&out_b[(size_t)grow * M + ti * TILE + 4 * c4]) = v4;
            }
        }
    }
}

extern "C" void kernel_launch(void* const* d_in, const int* in_sizes, int n_in,
                              void* d_out, int out_size, void* d_ws, size_t ws_size,
                              hipStream_t stream) {
    const float* spatial  = (const float*)d_in[0];
    const float* temporal = (const float*)d_in[1];
    float* out = (float*)d_out;

    dim3 block(256);
    dim3 grid(NPAIR, Bsz);   // 171 x 16
    stgraph_kernel<<<grid, block, 0, stream>>>(spatial, temporal, out);
}